// Round 1
// baseline (943.339 us; speedup 1.0000x reference)
//
#include <hip/hip_runtime.h>
#include <hip/hip_fp16.h>

// Problem constants (b=8, s=4096, EMBED=1024, HEADS=16, HEAD_DIM=64)
#define NTOK 32768
#define NE   1024

typedef _Float16 half_t;
typedef _Float16 f16x8 __attribute__((ext_vector_type(8)));
typedef _Float16 f16x4 __attribute__((ext_vector_type(4)));
typedef float    f32x4 __attribute__((ext_vector_type(4)));

typedef __attribute__((address_space(1))) const unsigned int guint;
typedef __attribute__((address_space(3))) unsigned int luint;

__device__ __forceinline__ void async16(const void* g, void* l) {
    // 16B global -> LDS direct copy. LDS dest = wave-uniform base + lane*16.
    __builtin_amdgcn_global_load_lds((guint*)g, (luint*)l, 16, 0, 0);
}

// ---------------------------------------------------------------- convert
__global__ __launch_bounds__(256) void cvt_f32_f16(const float* __restrict__ s,
                                                   half_t* __restrict__ d, int n) {
    int i = (blockIdx.x * 256 + threadIdx.x) * 8;
    if (i >= n) return;
    float4 a = *(const float4*)(s + i);
    float4 b = *(const float4*)(s + i + 4);
    f16x8 h = {(_Float16)a.x, (_Float16)a.y, (_Float16)a.z, (_Float16)a.w,
               (_Float16)b.x, (_Float16)b.y, (_Float16)b.z, (_Float16)b.w};
    *(f16x8*)(d + i) = h;
}

// ---------------------------------------------------------------- GEMM C = A * B^T
// A: [M x 1024] f16 row-major, B: [1024 x 1024] f16 row-major (N x K).
// QKV mode: blockIdx.z selects weight/output slab; epilogue cos(acc+theta), f16 out.
// else: plain f32 store to d_out.
template <bool QKV>
__global__ __launch_bounds__(256) void gemm_bt(const half_t* __restrict__ A,
                                               const half_t* __restrict__ Bbase,
                                               void* __restrict__ Cout,
                                               const float* __restrict__ theta) {
    constexpr int K = 1024;
    __shared__ alignas(16) half_t As[128 * 64];  // 16 KB
    __shared__ alignas(16) half_t Bs[128 * 64];  // 16 KB

    const int tid  = threadIdx.x;
    const int wave = tid >> 6;
    const int lane = tid & 63;
    const int quad = lane >> 4;
    const int l16  = lane & 15;
    const int wr   = wave >> 1, wc = wave & 1;   // 2x2 waves, each 64x64
    const size_t m0 = (size_t)blockIdx.y * 128;
    const int    n0 = blockIdx.x * 128;

    const half_t* Bp = Bbase;
    if (QKV) Bp += (size_t)blockIdx.z * (size_t)(NE * NE);

    const half_t* Ag = A + m0 * K;
    const half_t* Bg = Bp + (size_t)n0 * K;

    const int ar = tid >> 3;        // staging row within 32-row group
    const int ac = (tid & 7) * 8;   // staging col (8 f16 = 16B)

    f32x4 acc[4][4];
#pragma unroll
    for (int i = 0; i < 4; ++i)
#pragma unroll
        for (int j = 0; j < 4; ++j) acc[i][j] = (f32x4){0.f, 0.f, 0.f, 0.f};

    for (int k0 = 0; k0 < K; k0 += 64) {
#pragma unroll
        for (int i = 0; i < 4; ++i)
            async16(Ag + (size_t)(i * 32 + ar) * K + (k0 + ac),
                    (char*)As + (i * 256 + wave * 64) * 16);
#pragma unroll
        for (int i = 0; i < 4; ++i)
            async16(Bg + (size_t)(i * 32 + ar) * K + (k0 + ac),
                    (char*)Bs + (i * 256 + wave * 64) * 16);
        __syncthreads();  // drains vmcnt (global_load_lds) + lgkm

#pragma unroll
        for (int kk = 0; kk < 64; kk += 32) {
            f16x8 af[4], bf[4];
#pragma unroll
            for (int t = 0; t < 4; ++t) {
                af[t] = *(const f16x8*)&As[(wr * 64 + t * 16 + l16) * 64 + kk + quad * 8];
                bf[t] = *(const f16x8*)&Bs[(wc * 64 + t * 16 + l16) * 64 + kk + quad * 8];
            }
#pragma unroll
            for (int mt = 0; mt < 4; ++mt)
#pragma unroll
                for (int nt = 0; nt < 4; ++nt)
                    acc[mt][nt] = __builtin_amdgcn_mfma_f32_16x16x32_f16(
                        af[mt], bf[nt], acc[mt][nt], 0, 0, 0);
        }
        __syncthreads();
    }

    // C/D layout: col = lane&15, row = quad*4 + reg  [verified m89]
    if (QKV) {
        half_t* C = (half_t*)Cout + (size_t)blockIdx.z * ((size_t)NTOK * NE);
#pragma unroll
        for (int nt = 0; nt < 4; ++nt) {
            const int n = n0 + wc * 64 + nt * 16 + l16;
            const float th = theta[n & 63];
#pragma unroll
            for (int mt = 0; mt < 4; ++mt) {
                const size_t mb = m0 + wr * 64 + mt * 16 + quad * 4;
#pragma unroll
                for (int r = 0; r < 4; ++r)
                    C[(mb + r) * NE + n] = (half_t)__cosf(acc[mt][nt][r] + th);
            }
        }
    } else {
        float* C = (float*)Cout;
#pragma unroll
        for (int nt = 0; nt < 4; ++nt) {
            const int n = n0 + wc * 64 + nt * 16 + l16;
#pragma unroll
            for (int mt = 0; mt < 4; ++mt) {
                const size_t mb = m0 + wr * 64 + mt * 16 + quad * 4;
#pragma unroll
                for (int r = 0; r < 4; ++r) C[(mb + r) * NE + n] = acc[mt][nt][r];
            }
        }
    }
}

// ---------------------------------------------------------------- per-token attention
// Attention across the 16 HEADS (16x16 scores, dot over HEAD_DIM=64). One block/token.
__global__ __launch_bounds__(256) void attn_kernel(const half_t* __restrict__ q,
                                                   const half_t* __restrict__ k,
                                                   const half_t* __restrict__ v,
                                                   half_t* __restrict__ out) {
    __shared__ float qs[1024], ks[1024], vs[1024];
    __shared__ float S[256], P[256];
    __shared__ float rmax[16], rinv[16];
    const int tid = threadIdx.x;
    const size_t base = (size_t)blockIdx.x * 1024;

    f16x4 hq = *(const f16x4*)(q + base + tid * 4);
    f16x4 hk = *(const f16x4*)(k + base + tid * 4);
    f16x4 hv = *(const f16x4*)(v + base + tid * 4);
#pragma unroll
    for (int z = 0; z < 4; ++z) {
        qs[tid * 4 + z] = (float)hq[z];
        ks[tid * 4 + z] = (float)hk[z];
        vs[tid * 4 + z] = (float)hv[z];
    }
    __syncthreads();

    const int i = tid >> 4, j = tid & 15;
    float s = 0.f;
#pragma unroll
    for (int d = 0; d < 64; ++d) s += qs[i * 64 + d] * ks[j * 64 + d];
    S[tid] = s * 0.125f;  // 1/sqrt(64)
    __syncthreads();

    if (tid < 16) {
        float mx = -1e30f;
        for (int jj = 0; jj < 16; ++jj) mx = fmaxf(mx, S[tid * 16 + jj]);
        float sm = 0.f;
        for (int jj = 0; jj < 16; ++jj) sm += __expf(S[tid * 16 + jj] - mx);
        rmax[tid] = mx;
        rinv[tid] = 1.f / sm;
    }
    __syncthreads();
    P[tid] = __expf(S[tid] - rmax[i]) * rinv[i];
    __syncthreads();

    const int d0 = (tid & 15) * 4;
    float o0 = 0.f, o1 = 0.f, o2 = 0.f, o3 = 0.f;
#pragma unroll
    for (int jj = 0; jj < 16; ++jj) {
        const float p = P[i * 16 + jj];
        const float* vr = &vs[jj * 64 + d0];
        o0 += p * vr[0]; o1 += p * vr[1]; o2 += p * vr[2]; o3 += p * vr[3];
    }
    f16x4 ho = {(_Float16)o0, (_Float16)o1, (_Float16)o2, (_Float16)o3};
    *(f16x4*)(out + base + i * 64 + d0) = ho;
}

// ---------------------------------------------------------------- launch
extern "C" void kernel_launch(void* const* d_in, const int* in_sizes, int n_in,
                              void* d_out, int out_size, void* d_ws, size_t ws_size,
                              hipStream_t stream) {
    // setup_inputs order: x, Wk, Wq, Wv, Wo, theta
    const float* x     = (const float*)d_in[0];
    const float* Wk    = (const float*)d_in[1];
    const float* Wq    = (const float*)d_in[2];
    const float* Wv    = (const float*)d_in[3];
    const float* Wo    = (const float*)d_in[4];
    const float* theta = (const float*)d_in[5];

    char* ws = (char*)d_ws;
    half_t* xh  = (half_t*)ws;                           // 64 MB (reused for attn_out)
    half_t* wh  = (half_t*)(ws + (size_t)(64 << 20));    // 8 MB: Wq,Wk,Wv,Wo f16
    half_t* qkv = (half_t*)(ws + (size_t)(72 << 20));    // 192 MB: q_q,k_q,v_q f16

    // fp32 -> fp16 converts
    cvt_f32_f16<<<NTOK * NE / 2048, 256, 0, stream>>>(x, xh, NTOK * NE);
    cvt_f32_f16<<<NE * NE / 2048, 256, 0, stream>>>(Wq, wh + 0 * NE * NE, NE * NE);
    cvt_f32_f16<<<NE * NE / 2048, 256, 0, stream>>>(Wk, wh + 1 * NE * NE, NE * NE);
    cvt_f32_f16<<<NE * NE / 2048, 256, 0, stream>>>(Wv, wh + 2 * NE * NE, NE * NE);
    cvt_f32_f16<<<NE * NE / 2048, 256, 0, stream>>>(Wo, wh + 3 * NE * NE, NE * NE);

    // q,k,v projections + cos(.+theta) epilogue, one launch (z selects W / output slab)
    gemm_bt<true><<<dim3(8, 256, 3), 256, 0, stream>>>(xh, wh, qkv, theta);

    // per-token attention over heads; writes into xh slab (x no longer needed)
    attn_kernel<<<NTOK, 256, 0, stream>>>(qkv, qkv + (size_t)NTOK * NE,
                                          qkv + 2 * (size_t)NTOK * NE, xh);

    // out = attn_out @ Wo^T  (fp32 store to d_out)
    gemm_bt<false><<<dim3(8, 256, 1), 256, 0, stream>>>(xh, wh + 3 * NE * NE, d_out, nullptr);
}

// Round 2
// 720.794 us; speedup vs baseline: 1.3088x; 1.3088x over previous
//
#include <hip/hip_runtime.h>
#include <hip/hip_fp16.h>

// Problem constants (b=8, s=4096, EMBED=1024, HEADS=16, HEAD_DIM=64)
#define NTOK 32768
#define NE   1024

typedef _Float16 half_t;
typedef _Float16 f16x8 __attribute__((ext_vector_type(8)));
typedef _Float16 f16x4 __attribute__((ext_vector_type(4)));
typedef float    f32x4 __attribute__((ext_vector_type(4)));

typedef __attribute__((address_space(1))) const unsigned int guint;
typedef __attribute__((address_space(3))) unsigned int luint;

__device__ __forceinline__ void async16(const void* g, void* l) {
    // 16B global -> LDS direct copy. LDS dest = wave-uniform base + lane*16.
    __builtin_amdgcn_global_load_lds((guint*)g, (luint*)l, 16, 0, 0);
}

// ---------------------------------------------------------------- convert
__global__ __launch_bounds__(256) void cvt_f32_f16(const float* __restrict__ s,
                                                   half_t* __restrict__ d, int n) {
    int i = (blockIdx.x * 256 + threadIdx.x) * 8;
    if (i >= n) return;
    float4 a = *(const float4*)(s + i);
    float4 b = *(const float4*)(s + i + 4);
    f16x8 h = {(_Float16)a.x, (_Float16)a.y, (_Float16)a.z, (_Float16)a.w,
               (_Float16)b.x, (_Float16)b.y, (_Float16)b.z, (_Float16)b.w};
    *(f16x8*)(d + i) = h;
}

// ---------------------------------------------------------------- GEMM C = A * B^T
// A: [M x 1024] f16 row-major, B: [1024 x 1024] f16 row-major (N x K).
// LDS tiles XOR-swizzled: row r's 16B chunk c lives at slot (c ^ (r&7)).
// Row stride is 128 B (= 32 banks), so unswizzled reads put all 16 lanes of a
// quad on one 4-bank group (16-way conflict, 7.55e7 conflict cycles measured
// in R1). Swizzle spreads the wave's b128 reads uniformly over all 32 banks.
template <bool QKV>
__global__ __launch_bounds__(256) void gemm_bt(const half_t* __restrict__ A,
                                               const half_t* __restrict__ Bbase,
                                               void* __restrict__ Cout,
                                               const float* __restrict__ theta) {
    constexpr int K = 1024;
    __shared__ alignas(16) half_t As[128 * 64];  // 16 KB
    __shared__ alignas(16) half_t Bs[128 * 64];  // 16 KB

    const int tid  = threadIdx.x;
    const int wave = tid >> 6;
    const int lane = tid & 63;
    const int quad = lane >> 4;
    const int l16  = lane & 15;
    const int sw   = l16 & 7;                    // row&7 for fragment rows
    const int wr   = wave >> 1, wc = wave & 1;   // 2x2 waves, each 64x64
    const size_t m0 = (size_t)blockIdx.y * 128;
    const int    n0 = blockIdx.x * 128;

    const half_t* Bp = Bbase;
    if (QKV) Bp += (size_t)blockIdx.z * (size_t)(NE * NE);

    const half_t* Ag = A + m0 * K;
    const half_t* Bg = Bp + (size_t)n0 * K;

    const int ar = tid >> 3;                            // staging row in 32-row group
    const int ac = ((tid & 7) ^ (ar & 7)) * 8;          // XOR-swizzled source chunk
    // (each 8-lane group still reads a full contiguous 128 B segment -> coalesced;
    //  LDS dest stays lane-contiguous as global_load_lds requires)

    f32x4 acc[4][4];
#pragma unroll
    for (int i = 0; i < 4; ++i)
#pragma unroll
        for (int j = 0; j < 4; ++j) acc[i][j] = (f32x4){0.f, 0.f, 0.f, 0.f};

    for (int k0 = 0; k0 < K; k0 += 64) {
#pragma unroll
        for (int i = 0; i < 4; ++i)
            async16(Ag + (size_t)(i * 32 + ar) * K + (k0 + ac),
                    (char*)As + (i * 256 + wave * 64) * 16);
#pragma unroll
        for (int i = 0; i < 4; ++i)
            async16(Bg + (size_t)(i * 32 + ar) * K + (k0 + ac),
                    (char*)Bs + (i * 256 + wave * 64) * 16);
        __syncthreads();  // drains vmcnt (global_load_lds) + lgkm

#pragma unroll
        for (int kk = 0; kk < 64; kk += 32) {
            f16x8 af[4], bf[4];
#pragma unroll
            for (int t = 0; t < 4; ++t) {
                const int swzA = (((kk >> 3) + quad) ^ sw) * 8;
                af[t] = *(const f16x8*)&As[(wr * 64 + t * 16 + l16) * 64 + swzA];
                bf[t] = *(const f16x8*)&Bs[(wc * 64 + t * 16 + l16) * 64 + swzA];
            }
#pragma unroll
            for (int mt = 0; mt < 4; ++mt)
#pragma unroll
                for (int nt = 0; nt < 4; ++nt)
                    acc[mt][nt] = __builtin_amdgcn_mfma_f32_16x16x32_f16(
                        af[mt], bf[nt], acc[mt][nt], 0, 0, 0);
        }
        __syncthreads();
    }

    // C/D layout: col = lane&15, row = quad*4 + reg  [verified m89]
    if (QKV) {
        half_t* C = (half_t*)Cout + (size_t)blockIdx.z * ((size_t)NTOK * NE);
#pragma unroll
        for (int nt = 0; nt < 4; ++nt) {
            const int n = n0 + wc * 64 + nt * 16 + l16;
            const float th = theta[n & 63];
#pragma unroll
            for (int mt = 0; mt < 4; ++mt) {
                const size_t mb = m0 + wr * 64 + mt * 16 + quad * 4;
#pragma unroll
                for (int r = 0; r < 4; ++r)
                    C[(mb + r) * NE + n] = (half_t)__cosf(acc[mt][nt][r] + th);
            }
        }
    } else {
        float* C = (float*)Cout;
#pragma unroll
        for (int nt = 0; nt < 4; ++nt) {
            const int n = n0 + wc * 64 + nt * 16 + l16;
#pragma unroll
            for (int mt = 0; mt < 4; ++mt) {
                const size_t mb = m0 + wr * 64 + mt * 16 + quad * 4;
#pragma unroll
                for (int r = 0; r < 4; ++r) C[(mb + r) * NE + n] = acc[mt][nt][r];
            }
        }
    }
}

// ---------------------------------------------------------------- per-token attention
// Attention across the 16 HEADS (16x16 scores, dot over HEAD_DIM=64).
// One block per token, thread (i,j) = (tid>>4, tid&15) owns score S[i][j].
// q,k staged TRANSPOSED [d][head] with stride 17: S-loop reads are then
// broadcast/16-distinct-bank (conflict-free) instead of R1's 16-way conflict.
// Softmax via width-16 shuffle butterflies (no serialized 16-thread section).
__global__ __launch_bounds__(256) void attn_kernel(const half_t* __restrict__ q,
                                                   const half_t* __restrict__ k,
                                                   const half_t* __restrict__ v,
                                                   half_t* __restrict__ out) {
    __shared__ float qs[64 * 17], ks[64 * 17];  // [d][head], padded stride
    __shared__ float vs[1024];                  // [head][d]
    __shared__ float P[16 * 17];
    const int tid = threadIdx.x;
    const size_t base = (size_t)blockIdx.x * 1024;
    const int h  = tid >> 4;         // head this thread loads
    const int dq = (tid & 15) * 4;   // d-chunk this thread loads

    f16x4 hq = *(const f16x4*)(q + base + tid * 4);
    f16x4 hk = *(const f16x4*)(k + base + tid * 4);
    f16x4 hv = *(const f16x4*)(v + base + tid * 4);
#pragma unroll
    for (int z = 0; z < 4; ++z) {
        qs[(dq + z) * 17 + h] = (float)hq[z];
        ks[(dq + z) * 17 + h] = (float)hk[z];
    }
    *(float4*)&vs[tid * 4] =
        (float4){(float)hv[0], (float)hv[1], (float)hv[2], (float)hv[3]};
    __syncthreads();

    const int i = h, j = tid & 15;
    float s = 0.f;
#pragma unroll
    for (int d = 0; d < 64; ++d) s += qs[d * 17 + i] * ks[d * 17 + j];
    s *= 0.125f;  // 1/sqrt(64)

    float mx = s;
#pragma unroll
    for (int o = 8; o; o >>= 1) mx = fmaxf(mx, __shfl_xor(mx, o, 16));
    float e = __expf(s - mx);
    float sum = e;
#pragma unroll
    for (int o = 8; o; o >>= 1) sum += __shfl_xor(sum, o, 16);
    P[i * 17 + j] = e / sum;
    __syncthreads();

    float4 o4 = {0.f, 0.f, 0.f, 0.f};
#pragma unroll
    for (int jj = 0; jj < 16; ++jj) {
        const float p = P[i * 17 + jj];
        const float4 vr = *(const float4*)&vs[jj * 64 + dq];
        o4.x += p * vr.x; o4.y += p * vr.y; o4.z += p * vr.z; o4.w += p * vr.w;
    }
    f16x4 ho = {(_Float16)o4.x, (_Float16)o4.y, (_Float16)o4.z, (_Float16)o4.w};
    *(f16x4*)(out + base + i * 64 + dq) = ho;
}

// ---------------------------------------------------------------- launch
extern "C" void kernel_launch(void* const* d_in, const int* in_sizes, int n_in,
                              void* d_out, int out_size, void* d_ws, size_t ws_size,
                              hipStream_t stream) {
    // setup_inputs order: x, Wk, Wq, Wv, Wo, theta
    const float* x     = (const float*)d_in[0];
    const float* Wk    = (const float*)d_in[1];
    const float* Wq    = (const float*)d_in[2];
    const float* Wv    = (const float*)d_in[3];
    const float* Wo    = (const float*)d_in[4];
    const float* theta = (const float*)d_in[5];

    char* ws = (char*)d_ws;
    half_t* xh  = (half_t*)ws;                           // 64 MB (reused for attn_out)
    half_t* wh  = (half_t*)(ws + (size_t)(64 << 20));    // 8 MB: Wq,Wk,Wv,Wo f16
    half_t* qkv = (half_t*)(ws + (size_t)(72 << 20));    // 192 MB: q_q,k_q,v_q f16

    // fp32 -> fp16 converts
    cvt_f32_f16<<<NTOK * NE / 2048, 256, 0, stream>>>(x, xh, NTOK * NE);
    cvt_f32_f16<<<NE * NE / 2048, 256, 0, stream>>>(Wq, wh + 0 * NE * NE, NE * NE);
    cvt_f32_f16<<<NE * NE / 2048, 256, 0, stream>>>(Wk, wh + 1 * NE * NE, NE * NE);
    cvt_f32_f16<<<NE * NE / 2048, 256, 0, stream>>>(Wv, wh + 2 * NE * NE, NE * NE);
    cvt_f32_f16<<<NE * NE / 2048, 256, 0, stream>>>(Wo, wh + 3 * NE * NE, NE * NE);

    // q,k,v projections + cos(.+theta) epilogue, one launch (z selects W / output slab)
    gemm_bt<true><<<dim3(8, 256, 3), 256, 0, stream>>>(xh, wh, qkv, theta);

    // per-token attention over heads; writes into xh slab (x no longer needed)
    attn_kernel<<<NTOK, 256, 0, stream>>>(qkv, qkv + (size_t)NTOK * NE,
                                          qkv + 2 * (size_t)NTOK * NE, xh);

    // out = attn_out @ Wo^T  (fp32 store to d_out)
    gemm_bt<false><<<dim3(8, 256, 1), 256, 0, stream>>>(xh, wh + 3 * NE * NE, d_out, nullptr);
}

// Round 4
// 637.550 us; speedup vs baseline: 1.4796x; 1.1306x over previous
//
#include <hip/hip_runtime.h>
#include <hip/hip_fp16.h>

// Problem constants (b=8, s=4096, EMBED=1024, HEADS=16, HEAD_DIM=64)
#define NTOK 32768
#define NE   1024

typedef _Float16 half_t;
typedef _Float16 f16x8 __attribute__((ext_vector_type(8)));
typedef _Float16 f16x4 __attribute__((ext_vector_type(4)));
typedef float    f32x4 __attribute__((ext_vector_type(4)));

typedef __attribute__((address_space(1))) const unsigned int guint;
typedef __attribute__((address_space(3))) unsigned int luint;

__device__ __forceinline__ void async16(const void* g, void* l) {
    __builtin_amdgcn_global_load_lds((guint*)g, (luint*)l, 16, 0, 0);
}

// ---------------------------------------------------------------- convert
__global__ __launch_bounds__(256) void cvt_f32_f16(const float* __restrict__ s,
                                                   half_t* __restrict__ d, int n) {
    int i = (blockIdx.x * 256 + threadIdx.x) * 8;
    if (i >= n) return;
    float4 a = *(const float4*)(s + i);
    float4 b = *(const float4*)(s + i + 4);
    f16x8 h = {(_Float16)a.x, (_Float16)a.y, (_Float16)a.z, (_Float16)a.w,
               (_Float16)b.x, (_Float16)b.y, (_Float16)b.z, (_Float16)b.w};
    *(f16x8*)(d + i) = h;
}

// ---------------------------------------------------------------- GEMM C = A * B^T
// A: [M x 1024] f16 row-major, B: [NZ x 1024 x 1024] f16 row-major (N x K).
// LDS XOR-swizzle (R2): kills the 16-way bank conflict of the 128 B row stride.
// XCD-aware decode (R3): all J=8*NZ blocks of one y-tile (A-tile) share id%8,
// so each XCD's L2 fills each 256 KB A-tile once (R2 measured 798 MB L2-fill
// vs ~70 MB ideal because the sharers were spread round-robin across XCDs).
template <bool QKV>
__global__ __launch_bounds__(256) void gemm_bt(const half_t* __restrict__ A,
                                               const half_t* __restrict__ Bbase,
                                               void* __restrict__ Cout,
                                               const float* __restrict__ theta) {
    constexpr int K = 1024;
    constexpr int J = QKV ? 24 : 8;  // (z,x) blocks per y-tile
    __shared__ alignas(16) half_t As[128 * 64];  // 16 KB
    __shared__ alignas(16) half_t Bs[128 * 64];  // 16 KB

    const int id   = blockIdx.x;
    const int xcd  = id & 7;        // block->XCD heuristic: id % 8
    const int slot = id >> 3;
    const int ygrp = slot / J;
    const int j    = slot - ygrp * J;
    const int ytile = ygrp * 8 + xcd;
    const int zsl  = QKV ? (j >> 3) : 0;
    const int xt   = j & 7;

    const int tid  = threadIdx.x;
    const int wave = tid >> 6;
    const int lane = tid & 63;
    const int quad = lane >> 4;
    const int l16  = lane & 15;
    const int sw   = l16 & 7;
    const int wr   = wave >> 1, wc = wave & 1;   // 2x2 waves, each 64x64
    const size_t m0 = (size_t)ytile * 128;
    const int    n0 = xt * 128;

    const half_t* Bp = Bbase + (size_t)zsl * (size_t)(NE * NE);
    const half_t* Ag = A + m0 * K;
    const half_t* Bg = Bp + (size_t)n0 * K;

    const int ar = tid >> 3;                    // staging row in 32-row group
    const int ac = ((tid & 7) ^ (ar & 7)) * 8;  // XOR-swizzled source chunk

    f32x4 acc[4][4];
#pragma unroll
    for (int i = 0; i < 4; ++i)
#pragma unroll
        for (int jj = 0; jj < 4; ++jj) acc[i][jj] = (f32x4){0.f, 0.f, 0.f, 0.f};

    for (int k0 = 0; k0 < K; k0 += 64) {
#pragma unroll
        for (int i = 0; i < 4; ++i)
            async16(Ag + (size_t)(i * 32 + ar) * K + (k0 + ac),
                    (char*)As + (i * 256 + wave * 64) * 16);
#pragma unroll
        for (int i = 0; i < 4; ++i)
            async16(Bg + (size_t)(i * 32 + ar) * K + (k0 + ac),
                    (char*)Bs + (i * 256 + wave * 64) * 16);
        __syncthreads();

#pragma unroll
        for (int kk = 0; kk < 64; kk += 32) {
            f16x8 af[4], bf[4];
#pragma unroll
            for (int t = 0; t < 4; ++t) {
                const int swz = (((kk >> 3) + quad) ^ sw) * 8;
                af[t] = *(const f16x8*)&As[(wr * 64 + t * 16 + l16) * 64 + swz];
                bf[t] = *(const f16x8*)&Bs[(wc * 64 + t * 16 + l16) * 64 + swz];
            }
#pragma unroll
            for (int mt = 0; mt < 4; ++mt)
#pragma unroll
                for (int nt = 0; nt < 4; ++nt)
                    acc[mt][nt] = __builtin_amdgcn_mfma_f32_16x16x32_f16(
                        af[mt], bf[nt], acc[mt][nt], 0, 0, 0);
        }
        __syncthreads();
    }

    // C/D layout: col = lane&15, row = quad*4 + reg  [m89]
    if (QKV) {
        half_t* C = (half_t*)Cout + (size_t)zsl * ((size_t)NTOK * NE);
#pragma unroll
        for (int nt = 0; nt < 4; ++nt) {
            const int n = n0 + wc * 64 + nt * 16 + l16;
            const float th = theta[n & 63];
#pragma unroll
            for (int mt = 0; mt < 4; ++mt) {
                const size_t mb = m0 + wr * 64 + mt * 16 + quad * 4;
#pragma unroll
                for (int r = 0; r < 4; ++r)
                    C[(mb + r) * NE + n] = (half_t)__cosf(acc[mt][nt][r] + th);
            }
        }
    } else {
        float* C = (float*)Cout;
#pragma unroll
        for (int nt = 0; nt < 4; ++nt) {
            const int n = n0 + wc * 64 + nt * 16 + l16;
#pragma unroll
            for (int mt = 0; mt < 4; ++mt) {
                const size_t mb = m0 + wr * 64 + mt * 16 + quad * 4;
#pragma unroll
                for (int r = 0; r < 4; ++r) C[(mb + r) * NE + n] = acc[mt][nt][r];
            }
        }
    }
}

// ---------------------------------------------------------------- MFMA attention
// One wave = one token, 4 tokens/block. Scores S[16x16] = q.k^T over d=64 via
// two 16x16x32 MFMAs; q/k fragments loaded DIRECTLY from global in A/B layout
// [m|n = lane&15][k = quad*8+j] (m120-verified). Softmax rows (=quad*4+r in
// C-layout) reduced with 16-wide shuffle butterflies. PV via four 16x16x16
// MFMAs (legacy intrinsic spelling: ...16x16x16f16, K=16 exact; A/B layout
// [m][k=quad*4+j]): P and v^T round-trip LDS with stride 20 (conflict-free,
// 8 B-aligned b64 frag reads). Replaces R2's scalar-LDS S-loop, which was
// LDS-throughput bound (~128 ds_read_b32/thread, est ~250 us).
__global__ __launch_bounds__(256) void attn_kernel(const half_t* __restrict__ q,
                                                   const half_t* __restrict__ k,
                                                   const half_t* __restrict__ v,
                                                   half_t* __restrict__ out) {
    __shared__ half_t vT[4][64][20];  // [wave][d][head j], pad->20
    __shared__ half_t Pl[4][16][20];  // [wave][i][j], pad->20
    const int tid  = threadIdx.x;
    const int w    = tid >> 6;
    const int lane = tid & 63;
    const int quad = lane >> 4;
    const int l16  = lane & 15;
    const size_t base = ((size_t)blockIdx.x * 4 + w) * 1024;

    // stage v transposed: lane covers head h = lane>>2, d-chunk (lane&3)*16
    {
        const int h = lane >> 2, d0 = (lane & 3) * 16;
        f16x8 va = *(const f16x8*)(v + base + h * 64 + d0);
        f16x8 vb = *(const f16x8*)(v + base + h * 64 + d0 + 8);
#pragma unroll
        for (int z = 0; z < 8; ++z) {
            vT[w][d0 + z][h]     = va[z];
            vT[w][d0 + 8 + z][h] = vb[z];
        }
    }

    // scores: frags straight from global (no LDS)
    f16x8 aq0 = *(const f16x8*)(q + base + l16 * 64 + quad * 8);
    f16x8 aq1 = *(const f16x8*)(q + base + l16 * 64 + 32 + quad * 8);
    f16x8 bk0 = *(const f16x8*)(k + base + l16 * 64 + quad * 8);
    f16x8 bk1 = *(const f16x8*)(k + base + l16 * 64 + 32 + quad * 8);
    f32x4 S = __builtin_amdgcn_mfma_f32_16x16x32_f16(aq0, bk0, (f32x4){0.f,0.f,0.f,0.f}, 0, 0, 0);
    S = __builtin_amdgcn_mfma_f32_16x16x32_f16(aq1, bk1, S, 0, 0, 0);

    // softmax over cols (l16) per row (quad*4+r); write P f16 to LDS
#pragma unroll
    for (int r = 0; r < 4; ++r) {
        float s = S[r] * 0.125f;  // 1/sqrt(64)
        float mx = s;
#pragma unroll
        for (int o = 8; o; o >>= 1) mx = fmaxf(mx, __shfl_xor(mx, o));
        float e = __expf(s - mx);
        float sum = e;
#pragma unroll
        for (int o = 8; o; o >>= 1) sum += __shfl_xor(sum, o);
        Pl[w][quad * 4 + r][l16] = (half_t)(e / sum);
    }
    __syncthreads();  // vT + Pl visible across lanes

    // PV: A = P [m=i][k=j], B = v^T [k=j][n=d], 4 d-chunks of 16
    f16x4 ap = *(const f16x4*)&Pl[w][l16][quad * 4];
#pragma unroll
    for (int c = 0; c < 4; ++c) {
        f16x4 bv = *(const f16x4*)&vT[w][c * 16 + l16][quad * 4];
        f32x4 O = __builtin_amdgcn_mfma_f32_16x16x16f16(ap, bv, (f32x4){0.f,0.f,0.f,0.f}, 0, 0, 0);
#pragma unroll
        for (int r = 0; r < 4; ++r)
            out[base + (quad * 4 + r) * 64 + c * 16 + l16] = (half_t)O[r];
    }
}

// ---------------------------------------------------------------- launch
extern "C" void kernel_launch(void* const* d_in, const int* in_sizes, int n_in,
                              void* d_out, int out_size, void* d_ws, size_t ws_size,
                              hipStream_t stream) {
    // setup_inputs order: x, Wk, Wq, Wv, Wo, theta
    const float* x     = (const float*)d_in[0];
    const float* Wk    = (const float*)d_in[1];
    const float* Wq    = (const float*)d_in[2];
    const float* Wv    = (const float*)d_in[3];
    const float* Wo    = (const float*)d_in[4];
    const float* theta = (const float*)d_in[5];

    char* ws = (char*)d_ws;
    half_t* xh  = (half_t*)ws;                           // 64 MB (reused for attn_out)
    half_t* wh  = (half_t*)(ws + (size_t)(64 << 20));    // 8 MB: Wq,Wk,Wv,Wo f16
    half_t* qkv = (half_t*)(ws + (size_t)(72 << 20));    // 192 MB: q_q,k_q,v_q f16

    cvt_f32_f16<<<NTOK * NE / 2048, 256, 0, stream>>>(x, xh, NTOK * NE);
    cvt_f32_f16<<<NE * NE / 2048, 256, 0, stream>>>(Wq, wh + 0 * NE * NE, NE * NE);
    cvt_f32_f16<<<NE * NE / 2048, 256, 0, stream>>>(Wk, wh + 1 * NE * NE, NE * NE);
    cvt_f32_f16<<<NE * NE / 2048, 256, 0, stream>>>(Wv, wh + 2 * NE * NE, NE * NE);
    cvt_f32_f16<<<NE * NE / 2048, 256, 0, stream>>>(Wo, wh + 3 * NE * NE, NE * NE);

    // q,k,v projections + cos(.+theta): 1-D grid 8 xcd * 32 ygrp * 24 (z,x)
    gemm_bt<true><<<6144, 256, 0, stream>>>(xh, wh, qkv, theta);

    // per-token attention over heads (4 tokens/block)
    attn_kernel<<<NTOK / 4, 256, 0, stream>>>(qkv, qkv + (size_t)NTOK * NE,
                                              qkv + 2 * (size_t)NTOK * NE, xh);

    // out = attn_out @ Wo^T: grid 8 * 32 * 8
    gemm_bt<false><<<2048, 256, 0, stream>>>(xh, wh + 3 * NE * NE, d_out, nullptr);
}